// Round 13
// baseline (182.375 us; speedup 1.0000x reference)
//
#include <hip/hip_runtime.h>
#include <math.h>

#define NU_F 0.0031830988618379067f
#define HS 136   // halves per H row: 17*8 -> 16B-aligned, odd 16B-stride = bank-balanced

typedef __attribute__((ext_vector_type(8))) _Float16 half8;
typedef __attribute__((ext_vector_type(4))) _Float16 half4;
typedef __attribute__((ext_vector_type(16))) float f32x16;

// tanh via exp2 + fast rcp: ~5 VALU (2 on trans pipe). inf-safe: e=inf -> 1, e=0 -> -1.
__device__ __forceinline__ float fast_tanh(float x) {
    const float e = __builtin_amdgcn_exp2f(x * 2.8853900817779268f);  // e^(2x)
    const float r = __builtin_amdgcn_rcpf(e + 1.f);
    return fmaf(-2.f, r, 1.f);
}

// ---------------------------------------------------------------------------
// Weight prep: W[l][k][n] fp32 -> k-tiled fp16:
//   idx = l*16384 + (k>>4)*2048 + n*16 + (k&15)
// ---------------------------------------------------------------------------
__global__ void prep_kernel(const float* __restrict__ W1,
                            const float* __restrict__ W2,
                            const float* __restrict__ W3,
                            _Float16* __restrict__ ws)
{
    const int g = blockIdx.x * 256 + threadIdx.x;   // 0..49151
    const int l = g >> 14;
    const int r = g & 16383;
    const int n = r & 127;
    const int k = r >> 7;
    const float* W = (l == 0) ? W1 : (l == 1) ? W2 : W3;
    const float w = W[k * 128 + n];
    ws[l * 16384 + (k >> 4) * 2048 + n * 16 + (k & 15)] = (_Float16)w;
}

// ---------------------------------------------------------------------------
// Blocks 0..8191: equation, 16 pts (M=64 rows, m = 4p + channel).
// Blocks 8192..8319: init/bound forward-only, 64 pts (m = p).
// Wave w = (mhalf = w>>1, nhalf = w&1): m-tile [32mhalf,+32) x features
// [64nhalf,+64). A-frags read once per wave (deduped); whole layer's B in
// 16 named half8 regs loaded back-to-back at layer start (R12-proven).
// ---------------------------------------------------------------------------
__launch_bounds__(256, 4)
__global__ void pinn_kernel(const float* __restrict__ tx_eq,
                            const float* __restrict__ tx_init,
                            const float* __restrict__ tx_bnd,
                            const float* __restrict__ W0, const float* __restrict__ b0,
                            const float* __restrict__ b1, const float* __restrict__ b2,
                            const float* __restrict__ b3,
                            const float* __restrict__ W4, const float* __restrict__ b4,
                            const _Float16* __restrict__ wt,
                            float* __restrict__ out)
{
    __shared__ _Float16 Hh[64][HS];   // 17.4 KB, in-place across layers

    const int tid   = threadIdx.x;
    const int blk   = blockIdx.x;
    const bool is_eq = (blk < 8192);
    const int w     = tid >> 6;
    const int lane  = tid & 63;
    const int col   = lane & 31;
    const int khalf = lane >> 5;
    const int mhalf = w >> 1;
    const int nhalf = w & 1;
    const int n0    = 64 * nhalf + col;        // acc0's feature column
    const int n1    = n0 + 32;                 // acc1's feature column
    const int arow  = 32 * mhalf + col;        // this wave's A-frag row
    const int wofs  = n0 * 16 + khalf * 8;

    // ---- input layer (K=2, pointwise, fp32) ----
    if (is_eq) {
        const int p  = tid >> 4;                 // 0..15
        const int f0 = (tid & 15) * 8;
        const float tv = tx_eq[blk * 32 + 2 * p];
        const float xv = tx_eq[blk * 32 + 2 * p + 1];
        float vch[4][8];
        #pragma unroll
        for (int j = 0; j < 8; ++j) {
            const int f = f0 + j;
            const float w0v = W0[f];             // dz/dt
            const float w1v = W0[128 + f];       // dz/dx
            const float z = fmaf(tv, w0v, fmaf(xv, w1v, b0[f]));
            const float a = fast_tanh(z);
            const float s = 1.f - a * a;
            vch[0][j] = a;
            vch[1][j] = s * w0v;
            vch[2][j] = s * w1v;
            vch[3][j] = -2.f * a * s * w1v * w1v;
        }
        const int m0 = 4 * p;
        #pragma unroll
        for (int c = 0; c < 4; ++c) {
            half8 hh;
            #pragma unroll
            for (int j = 0; j < 8; ++j) hh[j] = (_Float16)vch[c][j];
            *(half8*)&Hh[m0 + c][f0] = hh;
        }
    } else {
        const int p  = tid >> 2;                 // 0..63 == row m
        const int f0 = (tid & 3) * 32;
        const int gp = (blk - 8192) * 64 + p;
        const float* src = (gp < 4096) ? tx_init : tx_bnd;
        const int idx = (gp < 4096) ? gp : gp - 4096;
        const float tv = src[2 * idx];
        const float xv = src[2 * idx + 1];
        #pragma unroll
        for (int g = 0; g < 4; ++g) {
            half8 hh;
            #pragma unroll
            for (int j = 0; j < 8; ++j) {
                const int f = f0 + 8 * g + j;
                hh[j] = (_Float16)fast_tanh(fmaf(tv, W0[f], fmaf(xv, W0[128 + f], b0[f])));
            }
            *(half8*)&Hh[p][f0 + 8 * g] = hh;
        }
    }
    __syncthreads();

    const float* barr[3] = {b1, b2, b3};

    #pragma unroll 1
    for (int layer = 0; layer < 3; ++layer) {
        const _Float16* __restrict__ ph = wt + layer * 16384 + wofs;
        const float bias0 = barr[layer][n0];
        const float bias1 = barr[layer][n1];

        // whole layer's B (this wave's 64 features) in 16 named registers
        half8 qa0 = *(const half8*)(ph);
        half8 qb0 = *(const half8*)(ph + 512);
        half8 qa1 = *(const half8*)(ph + 2048);
        half8 qb1 = *(const half8*)(ph + 2560);
        half8 qa2 = *(const half8*)(ph + 4096);
        half8 qb2 = *(const half8*)(ph + 4608);
        half8 qa3 = *(const half8*)(ph + 6144);
        half8 qb3 = *(const half8*)(ph + 6656);
        half8 qa4 = *(const half8*)(ph + 8192);
        half8 qb4 = *(const half8*)(ph + 8704);
        half8 qa5 = *(const half8*)(ph + 10240);
        half8 qb5 = *(const half8*)(ph + 10752);
        half8 qa6 = *(const half8*)(ph + 12288);
        half8 qb6 = *(const half8*)(ph + 12800);
        half8 qa7 = *(const half8*)(ph + 14336);
        half8 qb7 = *(const half8*)(ph + 14848);

        f32x16 acc0, acc1;
        #pragma unroll
        for (int e = 0; e < 16; ++e) { acc0[e] = 0.f; acc1[e] = 0.f; }

#define KSTEP(KT, QA, QB)                                                     \
        {                                                                     \
            const int k0 = KT * 16 + khalf * 8;                               \
            const half8 ah = *(const half8*)&Hh[arow][k0];                    \
            acc0 = __builtin_amdgcn_mfma_f32_32x32x16_f16(ah, QA, acc0, 0, 0, 0); \
            acc1 = __builtin_amdgcn_mfma_f32_32x32x16_f16(ah, QB, acc1, 0, 0, 0); \
        }
        KSTEP(0, qa0, qb0) KSTEP(1, qa1, qb1) KSTEP(2, qa2, qb2) KSTEP(3, qa3, qb3)
        KSTEP(4, qa4, qb4) KSTEP(5, qa5, qb5) KSTEP(6, qa6, qb6) KSTEP(7, qa7, qb7)
#undef KSTEP

        // epilogue COMPUTE (registers only, before the barrier). C-layout:
        // reg group 4g..4g+3 = rows 32mhalf+8g+4khalf+{0..3} = the 4 derivative
        // channels of one point (eq) -> chain rule in registers.
        half4 h16[2][4];
        #pragma unroll
        for (int a = 0; a < 2; ++a) {
            const float bias = a ? bias1 : bias0;
            #pragma unroll
            for (int g = 0; g < 4; ++g) {
                const float A0 = (a ? acc1 : acc0)[4 * g + 0];
                const float A1 = (a ? acc1 : acc0)[4 * g + 1];
                const float A2 = (a ? acc1 : acc0)[4 * g + 2];
                const float A3 = (a ? acc1 : acc0)[4 * g + 3];
                half4 hv;
                if (is_eq) {
                    const float t = fast_tanh(A0 + bias);
                    const float s = 1.f - t * t;
                    hv[0] = (_Float16)t;
                    hv[1] = (_Float16)(s * A1);
                    hv[2] = (_Float16)(s * A2);
                    hv[3] = (_Float16)fmaf(s, A3, -2.f * t * s * A2 * A2);
                } else {
                    hv[0] = (_Float16)fast_tanh(A0 + bias);
                    hv[1] = (_Float16)fast_tanh(A1 + bias);
                    hv[2] = (_Float16)fast_tanh(A2 + bias);
                    hv[3] = (_Float16)fast_tanh(A3 + bias);
                }
                h16[a][g] = hv;
            }
        }

        __syncthreads();   // all reads of H done -> in-place overwrite safe

        // epilogue STORE (the only work between the two barriers)
        #pragma unroll
        for (int a = 0; a < 2; ++a) {
            const int nc = a ? n1 : n0;
            #pragma unroll
            for (int g = 0; g < 4; ++g) {
                const int mrow0 = 32 * mhalf + 8 * g + 4 * khalf;
                Hh[mrow0 + 0][nc] = h16[a][g][0];
                Hh[mrow0 + 1][nc] = h16[a][g][1];
                Hh[mrow0 + 2][nc] = h16[a][g][2];
                Hh[mrow0 + 3][nc] = h16[a][g][3];
            }
        }
        __syncthreads();
    }

    // ---- final layer (128 -> 1): thread t reduces k-quarter (t&3) of row t>>2
    {
        const float b4v = b4[0];
        const int m = tid >> 2;
        const int q = tid & 3;
        float dot = 0.f;
        #pragma unroll
        for (int g = 0; g < 4; ++g) {
            const int f = 32 * q + 8 * g;
            const half8 hh = *(const half8*)&Hh[m][f];
            const float4 wa = *(const float4*)&W4[f];
            const float4 wb = *(const float4*)&W4[f + 4];
            dot = fmaf((float)hh[0], wa.x, dot);
            dot = fmaf((float)hh[1], wa.y, dot);
            dot = fmaf((float)hh[2], wa.z, dot);
            dot = fmaf((float)hh[3], wa.w, dot);
            dot = fmaf((float)hh[4], wb.x, dot);
            dot = fmaf((float)hh[5], wb.y, dot);
            dot = fmaf((float)hh[6], wb.z, dot);
            dot = fmaf((float)hh[7], wb.w, dot);
        }
        dot += __shfl_xor(dot, 1);   // reduce across the 4 k-quarters
        dot += __shfl_xor(dot, 2);   // full row-dot at all 4 lanes of the row

        if (is_eq) {
            // wave w holds rows [16w,16w+16) = points [4w,4w+4); lane = 16p' + 4c + q
            const float uu   = __shfl(dot, (lane & 48) + 0)  + b4v;
            const float utv  = __shfl(dot, (lane & 48) + 4);
            const float uxv  = __shfl(dot, (lane & 48) + 8);
            const float uxxv = __shfl(dot, (lane & 48) + 12);
            if ((lane & 15) == 0)
                out[blk * 16 + 4 * w + (lane >> 4)] = fmaf(uu, uxv, utv) - NU_F * uxxv;
        } else {
            if (q == 0)
                out[131072 + (blk - 8192) * 64 + m] = dot + b4v;
        }
    }
}

extern "C" void kernel_launch(void* const* d_in, const int* in_sizes, int n_in,
                              void* d_out, int out_size, void* d_ws, size_t ws_size,
                              hipStream_t stream)
{
    const float* tx_eq   = (const float*)d_in[0];
    const float* tx_init = (const float*)d_in[1];
    const float* tx_bnd  = (const float*)d_in[2];
    const float* W0 = (const float*)d_in[3];
    const float* b0 = (const float*)d_in[4];
    const float* W1 = (const float*)d_in[5];
    const float* b1 = (const float*)d_in[6];
    const float* W2 = (const float*)d_in[7];
    const float* b2 = (const float*)d_in[8];
    const float* W3 = (const float*)d_in[9];
    const float* b3 = (const float*)d_in[10];
    const float* W4 = (const float*)d_in[11];
    const float* b4 = (const float*)d_in[12];
    float* out = (float*)d_out;
    _Float16* wt = (_Float16*)d_ws;   // needs 98304 B

    hipLaunchKernelGGL(prep_kernel, dim3(192), dim3(256), 0, stream, W1, W2, W3, wt);
    // 8192 eq blocks (16 pts) + 128 ib blocks (64 pts)
    hipLaunchKernelGGL(pinn_kernel, dim3(8320), dim3(256), 0, stream,
                       tx_eq, tx_init, tx_bnd, W0, b0, b1, b2, b3, W4, b4,
                       (const _Float16*)wt, out);
}

// Round 14
// 174.464 us; speedup vs baseline: 1.0453x; 1.0453x over previous
//
#include <hip/hip_runtime.h>
#include <math.h>

#define NU_F 0.0031830988618379067f
#define HS 136   // halves per H row: 17*8 -> 16B-aligned, odd 16B-stride = bank-balanced

typedef __attribute__((ext_vector_type(8))) _Float16 half8;
typedef __attribute__((ext_vector_type(4))) _Float16 half4;
typedef __attribute__((ext_vector_type(16))) float f32x16;

// tanh via exp2 + fast rcp: ~5 VALU (2 on trans pipe). inf-safe: e=inf -> 1, e=0 -> -1.
__device__ __forceinline__ float fast_tanh(float x) {
    const float e = __builtin_amdgcn_exp2f(x * 2.8853900817779268f);  // e^(2x)
    const float r = __builtin_amdgcn_rcpf(e + 1.f);
    return fmaf(-2.f, r, 1.f);
}

// ---------------------------------------------------------------------------
// Weight prep: W[l][k][n] fp32 -> k-tiled fp16:
//   idx = l*16384 + (k>>4)*2048 + n*16 + (k&15)
// A wave's per-kt B-read (16 halves/lane, n-contiguous) is one 1KB block.
// ---------------------------------------------------------------------------
__global__ void prep_kernel(const float* __restrict__ W1,
                            const float* __restrict__ W2,
                            const float* __restrict__ W3,
                            _Float16* __restrict__ ws)
{
    const int g = blockIdx.x * 256 + threadIdx.x;   // 0..49151
    const int l = g >> 14;
    const int r = g & 16383;
    const int n = r & 127;
    const int k = r >> 7;
    const float* W = (l == 0) ? W1 : (l == 1) ? W2 : W3;
    const float w = W[k * 128 + n];
    ws[l * 16384 + (k >> 4) * 2048 + n * 16 + (k & 15)] = (_Float16)w;
}

// ---------------------------------------------------------------------------
// Blocks 0..8191: equation, 16 pts (M=64 rows, m = 4p + channel).
// Blocks 8192..8319: init/bound forward-only, 64 pts (m = p).
// Wave w computes cols [32w,32w+32) for all 64 rows (mt=0,1).
// Fully unrolled 3 hidden layers; layer l+1's B-loads are issued right after
// layer l's K-loop so the epilogue+barrier hides the L2 latency.
// ---------------------------------------------------------------------------
__launch_bounds__(256, 6)
__global__ void pinn_kernel(const float* __restrict__ tx_eq,
                            const float* __restrict__ tx_init,
                            const float* __restrict__ tx_bnd,
                            const float* __restrict__ W0, const float* __restrict__ b0,
                            const float* __restrict__ b1, const float* __restrict__ b2,
                            const float* __restrict__ b3,
                            const float* __restrict__ W4, const float* __restrict__ b4,
                            const _Float16* __restrict__ wt,
                            float* __restrict__ out)
{
    __shared__ _Float16 Hh[64][HS];   // 17.4 KB, in-place across layers

    const int tid   = threadIdx.x;
    const int blk   = blockIdx.x;
    const bool is_eq = (blk < 8192);
    const int w     = tid >> 6;
    const int lane  = tid & 63;
    const int col   = lane & 31;
    const int khalf = lane >> 5;
    const int ncol  = 32 * w + col;
    const int wofs  = ncol * 16 + khalf * 8;

    const _Float16* __restrict__ ph0 = wt + wofs;
    const _Float16* __restrict__ ph1 = ph0 + 16384;
    const _Float16* __restrict__ ph2 = ph1 + 16384;

    // layer-0 B + all biases issued before input-layer compute (latency hidden)
    half8 q0 = *(const half8*)(ph0);
    half8 q1 = *(const half8*)(ph0 + 2048);
    half8 q2 = *(const half8*)(ph0 + 4096);
    half8 q3 = *(const half8*)(ph0 + 6144);
    half8 q4 = *(const half8*)(ph0 + 8192);
    half8 q5 = *(const half8*)(ph0 + 10240);
    half8 q6 = *(const half8*)(ph0 + 12288);
    half8 q7 = *(const half8*)(ph0 + 14336);
    const float biasA = b1[ncol];
    const float biasB = b2[ncol];
    const float biasC = b3[ncol];

    // ---- input layer (K=2, pointwise, fp32) ----
    if (is_eq) {
        const int p  = tid >> 4;                 // 0..15
        const int f0 = (tid & 15) * 8;
        const float tv = tx_eq[blk * 32 + 2 * p];
        const float xv = tx_eq[blk * 32 + 2 * p + 1];
        float vch[4][8];
        #pragma unroll
        for (int j = 0; j < 8; ++j) {
            const int f = f0 + j;
            const float w0v = W0[f];             // dz/dt
            const float w1v = W0[128 + f];       // dz/dx
            const float z = fmaf(tv, w0v, fmaf(xv, w1v, b0[f]));
            const float a = fast_tanh(z);
            const float s = 1.f - a * a;
            vch[0][j] = a;
            vch[1][j] = s * w0v;
            vch[2][j] = s * w1v;
            vch[3][j] = -2.f * a * s * w1v * w1v;
        }
        const int m0 = 4 * p;
        #pragma unroll
        for (int c = 0; c < 4; ++c) {
            half8 hh;
            #pragma unroll
            for (int j = 0; j < 8; ++j) hh[j] = (_Float16)vch[c][j];
            *(half8*)&Hh[m0 + c][f0] = hh;
        }
    } else {
        const int p  = tid >> 2;                 // 0..63 == row m
        const int f0 = (tid & 3) * 32;
        const int gp = (blk - 8192) * 64 + p;
        const float* src = (gp < 4096) ? tx_init : tx_bnd;
        const int idx = (gp < 4096) ? gp : gp - 4096;
        const float tv = src[2 * idx];
        const float xv = src[2 * idx + 1];
        #pragma unroll
        for (int g = 0; g < 4; ++g) {
            half8 hh;
            #pragma unroll
            for (int j = 0; j < 8; ++j) {
                const int f = f0 + 8 * g + j;
                hh[j] = (_Float16)fast_tanh(fmaf(tv, W0[f], fmaf(xv, W0[128 + f], b0[f])));
            }
            *(half8*)&Hh[p][f0 + 8 * g] = hh;
        }
    }
    __syncthreads();

    // one hidden layer, straight-line. Issues the NEXT layer's B-loads right
    // after the K-loop (epilogue + barrier hide the latency).
#define LAYER(BIAS, HAS_NEXT, PH_NEXT)                                        \
    {                                                                         \
        f32x16 acc0, acc1;                                                    \
        _Pragma("unroll")                                                     \
        for (int e = 0; e < 16; ++e) { acc0[e] = 0.f; acc1[e] = 0.f; }        \
        _Pragma("unroll")                                                     \
        for (int kt = 0; kt < 8; ++kt) {                                      \
            const int k0 = kt * 16 + khalf * 8;                               \
            const half8 ah0 = *(const half8*)&Hh[col][k0];                    \
            const half8 ah1 = *(const half8*)&Hh[32 + col][k0];               \
            const half8 qq = (kt == 0) ? q0 : (kt == 1) ? q1 : (kt == 2) ? q2 \
                           : (kt == 3) ? q3 : (kt == 4) ? q4 : (kt == 5) ? q5 \
                           : (kt == 6) ? q6 : q7;                             \
            acc0 = __builtin_amdgcn_mfma_f32_32x32x16_f16(ah0, qq, acc0, 0, 0, 0); \
            acc1 = __builtin_amdgcn_mfma_f32_32x32x16_f16(ah1, qq, acc1, 0, 0, 0); \
        }                                                                     \
        if (HAS_NEXT) {                                                       \
            q0 = *(const half8*)(PH_NEXT);                                    \
            q1 = *(const half8*)(PH_NEXT + 2048);                             \
            q2 = *(const half8*)(PH_NEXT + 4096);                             \
            q3 = *(const half8*)(PH_NEXT + 6144);                             \
            q4 = *(const half8*)(PH_NEXT + 8192);                             \
            q5 = *(const half8*)(PH_NEXT + 10240);                            \
            q6 = *(const half8*)(PH_NEXT + 12288);                            \
            q7 = *(const half8*)(PH_NEXT + 14336);                            \
        }                                                                     \
        half4 h16[2][4];                                                      \
        _Pragma("unroll")                                                     \
        for (int mt = 0; mt < 2; ++mt)                                        \
            _Pragma("unroll")                                                 \
            for (int g = 0; g < 4; ++g) {                                     \
                const float A0 = (mt ? acc1 : acc0)[4 * g + 0];               \
                const float A1 = (mt ? acc1 : acc0)[4 * g + 1];               \
                const float A2 = (mt ? acc1 : acc0)[4 * g + 2];               \
                const float A3 = (mt ? acc1 : acc0)[4 * g + 3];               \
                half4 hv;                                                     \
                if (is_eq) {                                                  \
                    const float t = fast_tanh(A0 + (BIAS));                   \
                    const float s = 1.f - t * t;                              \
                    hv[0] = (_Float16)t;                                      \
                    hv[1] = (_Float16)(s * A1);                               \
                    hv[2] = (_Float16)(s * A2);                               \
                    hv[3] = (_Float16)fmaf(s, A3, -2.f * t * s * A2 * A2);    \
                } else {                                                      \
                    hv[0] = (_Float16)fast_tanh(A0 + (BIAS));                 \
                    hv[1] = (_Float16)fast_tanh(A1 + (BIAS));                 \
                    hv[2] = (_Float16)fast_tanh(A2 + (BIAS));                 \
                    hv[3] = (_Float16)fast_tanh(A3 + (BIAS));                 \
                }                                                             \
                h16[mt][g] = hv;                                              \
            }                                                                 \
        __syncthreads();                                                      \
        _Pragma("unroll")                                                     \
        for (int mt = 0; mt < 2; ++mt)                                        \
            _Pragma("unroll")                                                 \
            for (int g = 0; g < 4; ++g) {                                     \
                const int mrow0 = mt * 32 + 8 * g + 4 * khalf;                \
                Hh[mrow0 + 0][ncol] = h16[mt][g][0];                          \
                Hh[mrow0 + 1][ncol] = h16[mt][g][1];                          \
                Hh[mrow0 + 2][ncol] = h16[mt][g][2];                          \
                Hh[mrow0 + 3][ncol] = h16[mt][g][3];                          \
            }                                                                 \
        __syncthreads();                                                      \
    }

    LAYER(biasA, 1, ph1)
    LAYER(biasB, 1, ph2)
    LAYER(biasC, 0, ph2)
#undef LAYER

    // ---- final layer (128 -> 1): thread t reduces k-quarter (t&3) of row t>>2
    {
        const float b4v = b4[0];
        const int m = tid >> 2;
        const int q = tid & 3;
        float dot = 0.f;
        #pragma unroll
        for (int g = 0; g < 4; ++g) {
            const int f = 32 * q + 8 * g;
            const half8 hh = *(const half8*)&Hh[m][f];
            const float4 wa = *(const float4*)&W4[f];
            const float4 wb = *(const float4*)&W4[f + 4];
            dot = fmaf((float)hh[0], wa.x, dot);
            dot = fmaf((float)hh[1], wa.y, dot);
            dot = fmaf((float)hh[2], wa.z, dot);
            dot = fmaf((float)hh[3], wa.w, dot);
            dot = fmaf((float)hh[4], wb.x, dot);
            dot = fmaf((float)hh[5], wb.y, dot);
            dot = fmaf((float)hh[6], wb.z, dot);
            dot = fmaf((float)hh[7], wb.w, dot);
        }
        dot += __shfl_xor(dot, 1);   // reduce across the 4 k-quarters
        dot += __shfl_xor(dot, 2);   // full row-dot at all 4 lanes of the row

        if (is_eq) {
            // wave w holds rows [16w,16w+16) = points [4w,4w+4); lane = 16p' + 4c + q
            const float uu   = __shfl(dot, (lane & 48) + 0)  + b4v;
            const float utv  = __shfl(dot, (lane & 48) + 4);
            const float uxv  = __shfl(dot, (lane & 48) + 8);
            const float uxxv = __shfl(dot, (lane & 48) + 12);
            if ((lane & 15) == 0)
                out[blk * 16 + 4 * w + (lane >> 4)] = fmaf(uu, uxv, utv) - NU_F * uxxv;
        } else {
            if (q == 0)
                out[131072 + (blk - 8192) * 64 + m] = dot + b4v;
        }
    }
}

extern "C" void kernel_launch(void* const* d_in, const int* in_sizes, int n_in,
                              void* d_out, int out_size, void* d_ws, size_t ws_size,
                              hipStream_t stream)
{
    const float* tx_eq   = (const float*)d_in[0];
    const float* tx_init = (const float*)d_in[1];
    const float* tx_bnd  = (const float*)d_in[2];
    const float* W0 = (const float*)d_in[3];
    const float* b0 = (const float*)d_in[4];
    const float* W1 = (const float*)d_in[5];
    const float* b1 = (const float*)d_in[6];
    const float* W2 = (const float*)d_in[7];
    const float* b2 = (const float*)d_in[8];
    const float* W3 = (const float*)d_in[9];
    const float* b3 = (const float*)d_in[10];
    const float* W4 = (const float*)d_in[11];
    const float* b4 = (const float*)d_in[12];
    float* out = (float*)d_out;
    _Float16* wt = (_Float16*)d_ws;   // needs 98304 B

    hipLaunchKernelGGL(prep_kernel, dim3(192), dim3(256), 0, stream, W1, W2, W3, wt);
    // 8192 eq blocks (16 pts) + 128 ib blocks (64 pts)
    hipLaunchKernelGGL(pinn_kernel, dim3(8320), dim3(256), 0, stream,
                       tx_eq, tx_init, tx_bnd, W0, b0, b1, b2, b3, W4, b4,
                       (const _Float16*)wt, out);
}

// Round 15
// 166.380 us; speedup vs baseline: 1.0961x; 1.0486x over previous
//
#include <hip/hip_runtime.h>
#include <math.h>

#define NU_F 0.0031830988618379067f
#define HS 136   // halves per H row: 17*8 -> 16B-aligned, odd 16B-stride = bank-balanced

typedef __attribute__((ext_vector_type(8))) _Float16 half8;
typedef __attribute__((ext_vector_type(4))) _Float16 half4;
typedef __attribute__((ext_vector_type(16))) float f32x16;

// tanh via exp2 + fast rcp: ~5 VALU (2 on trans pipe). inf-safe: e=inf -> 1, e=0 -> -1.
__device__ __forceinline__ float fast_tanh(float x) {
    const float e = __builtin_amdgcn_exp2f(x * 2.8853900817779268f);  // e^(2x)
    const float r = __builtin_amdgcn_rcpf(e + 1.f);
    return fmaf(-2.f, r, 1.f);
}

// ---------------------------------------------------------------------------
// Weight prep: W[l][k][n] fp32 -> k-tiled fp16:
//   idx = l*16384 + (k>>4)*2048 + n*16 + (k&15)
// A wave's per-kt B-read (16 halves/lane, n-contiguous) is one 1KB block.
// ---------------------------------------------------------------------------
__global__ void prep_kernel(const float* __restrict__ W1,
                            const float* __restrict__ W2,
                            const float* __restrict__ W3,
                            _Float16* __restrict__ ws)
{
    const int g = blockIdx.x * 256 + threadIdx.x;   // 0..49151
    const int l = g >> 14;
    const int r = g & 16383;
    const int n = r & 127;
    const int k = r >> 7;
    const float* W = (l == 0) ? W1 : (l == 1) ? W2 : W3;
    const float w = W[k * 128 + n];
    ws[l * 16384 + (k >> 4) * 2048 + n * 16 + (k & 15)] = (_Float16)w;
}

// ---------------------------------------------------------------------------
// Blocks 0..4095: equation, 32 pts (M=128 rows, m = 4p + channel).
// Blocks 4096..4159: init/bound forward-only, 128 pts (m = p).
// Wave w computes cols [32w,32w+32) for all 128 rows (mt=0..3).
// R12-proven codegen: per-layer q0..q7 named reload (no cross-barrier B
// state), epilogue compute pre-barrier in registers, only b16 stores between
// barriers. M=128 halves the number of barrier phases per point.
// ---------------------------------------------------------------------------
__launch_bounds__(256, 4)
__global__ void pinn_kernel(const float* __restrict__ tx_eq,
                            const float* __restrict__ tx_init,
                            const float* __restrict__ tx_bnd,
                            const float* __restrict__ W0, const float* __restrict__ b0,
                            const float* __restrict__ b1, const float* __restrict__ b2,
                            const float* __restrict__ b3,
                            const float* __restrict__ W4, const float* __restrict__ b4,
                            const _Float16* __restrict__ wt,
                            float* __restrict__ out)
{
    __shared__ _Float16 Hh[128][HS];   // 34.8 KB, in-place across layers

    const int tid   = threadIdx.x;
    const int blk   = blockIdx.x;
    const bool is_eq = (blk < 4096);
    const int w     = tid >> 6;
    const int lane  = tid & 63;
    const int col   = lane & 31;
    const int khalf = lane >> 5;
    const int ncol  = 32 * w + col;
    const int wofs  = ncol * 16 + khalf * 8;

    // ---- input layer (K=2, pointwise, fp32) ----
    if (is_eq) {
        const int p  = tid >> 3;                 // 0..31
        const int f0 = (tid & 7) * 16;
        const float tv = tx_eq[blk * 64 + 2 * p];
        const float xv = tx_eq[blk * 64 + 2 * p + 1];
        const int m0 = 4 * p;
        #pragma unroll
        for (int half = 0; half < 2; ++half) {
            const int fb = f0 + 8 * half;
            float vch[4][8];
            #pragma unroll
            for (int j = 0; j < 8; ++j) {
                const int f = fb + j;
                const float w0v = W0[f];             // dz/dt
                const float w1v = W0[128 + f];       // dz/dx
                const float z = fmaf(tv, w0v, fmaf(xv, w1v, b0[f]));
                const float a = fast_tanh(z);
                const float s = 1.f - a * a;
                vch[0][j] = a;
                vch[1][j] = s * w0v;
                vch[2][j] = s * w1v;
                vch[3][j] = -2.f * a * s * w1v * w1v;
            }
            #pragma unroll
            for (int c = 0; c < 4; ++c) {
                half8 hh;
                #pragma unroll
                for (int j = 0; j < 8; ++j) hh[j] = (_Float16)vch[c][j];
                *(half8*)&Hh[m0 + c][fb] = hh;
            }
        }
    } else {
        const int p  = tid >> 1;                 // 0..127 == row m
        const int f0 = (tid & 1) * 64;
        const int gp = (blk - 4096) * 128 + p;
        const float* src = (gp < 4096) ? tx_init : tx_bnd;
        const int idx = (gp < 4096) ? gp : gp - 4096;
        const float tv = src[2 * idx];
        const float xv = src[2 * idx + 1];
        #pragma unroll
        for (int g = 0; g < 8; ++g) {
            half8 hh;
            #pragma unroll
            for (int j = 0; j < 8; ++j) {
                const int f = f0 + 8 * g + j;
                hh[j] = (_Float16)fast_tanh(fmaf(tv, W0[f], fmaf(xv, W0[128 + f], b0[f])));
            }
            *(half8*)&Hh[p][f0 + 8 * g] = hh;
        }
    }
    __syncthreads();

    const float* barr[3] = {b1, b2, b3};

    #pragma unroll 1
    for (int layer = 0; layer < 3; ++layer) {
        const _Float16* __restrict__ ph = wt + layer * 16384 + wofs;
        const float bias = barr[layer][ncol];

        // whole layer's B in 8 named registers; loads issued back-to-back.
        half8 q0 = *(const half8*)(ph);
        half8 q1 = *(const half8*)(ph + 2048);
        half8 q2 = *(const half8*)(ph + 4096);
        half8 q3 = *(const half8*)(ph + 6144);
        half8 q4 = *(const half8*)(ph + 8192);
        half8 q5 = *(const half8*)(ph + 10240);
        half8 q6 = *(const half8*)(ph + 12288);
        half8 q7 = *(const half8*)(ph + 14336);

        f32x16 acc0, acc1, acc2, acc3;
        #pragma unroll
        for (int e = 0; e < 16; ++e) {
            acc0[e] = 0.f; acc1[e] = 0.f; acc2[e] = 0.f; acc3[e] = 0.f;
        }

#define KSTEP(KT, Q)                                                          \
        {                                                                     \
            const int k0 = KT * 16 + khalf * 8;                               \
            const half8 ah0 = *(const half8*)&Hh[col][k0];                    \
            const half8 ah1 = *(const half8*)&Hh[32 + col][k0];               \
            const half8 ah2 = *(const half8*)&Hh[64 + col][k0];               \
            const half8 ah3 = *(const half8*)&Hh[96 + col][k0];               \
            acc0 = __builtin_amdgcn_mfma_f32_32x32x16_f16(ah0, Q, acc0, 0, 0, 0); \
            acc1 = __builtin_amdgcn_mfma_f32_32x32x16_f16(ah1, Q, acc1, 0, 0, 0); \
            acc2 = __builtin_amdgcn_mfma_f32_32x32x16_f16(ah2, Q, acc2, 0, 0, 0); \
            acc3 = __builtin_amdgcn_mfma_f32_32x32x16_f16(ah3, Q, acc3, 0, 0, 0); \
        }
        KSTEP(0, q0) KSTEP(1, q1) KSTEP(2, q2) KSTEP(3, q3)
        KSTEP(4, q4) KSTEP(5, q5) KSTEP(6, q6) KSTEP(7, q7)
#undef KSTEP

        // epilogue COMPUTE (registers only, before the barrier). C-layout:
        // reg group 4g..4g+3 = rows mt*32+8g+4khalf+{0..3} = the 4 derivative
        // channels of one point (eq) -> chain rule in registers.
        half4 h16[4][4];
        #pragma unroll
        for (int mt = 0; mt < 4; ++mt)
            #pragma unroll
            for (int g = 0; g < 4; ++g) {
                const float A0 = (mt == 0 ? acc0 : mt == 1 ? acc1 : mt == 2 ? acc2 : acc3)[4 * g + 0];
                const float A1 = (mt == 0 ? acc0 : mt == 1 ? acc1 : mt == 2 ? acc2 : acc3)[4 * g + 1];
                const float A2 = (mt == 0 ? acc0 : mt == 1 ? acc1 : mt == 2 ? acc2 : acc3)[4 * g + 2];
                const float A3 = (mt == 0 ? acc0 : mt == 1 ? acc1 : mt == 2 ? acc2 : acc3)[4 * g + 3];
                half4 hv;
                if (is_eq) {
                    const float t = fast_tanh(A0 + bias);
                    const float s = 1.f - t * t;
                    hv[0] = (_Float16)t;
                    hv[1] = (_Float16)(s * A1);
                    hv[2] = (_Float16)(s * A2);
                    hv[3] = (_Float16)fmaf(s, A3, -2.f * t * s * A2 * A2);
                } else {
                    hv[0] = (_Float16)fast_tanh(A0 + bias);
                    hv[1] = (_Float16)fast_tanh(A1 + bias);
                    hv[2] = (_Float16)fast_tanh(A2 + bias);
                    hv[3] = (_Float16)fast_tanh(A3 + bias);
                }
                h16[mt][g] = hv;
            }

        __syncthreads();   // all reads of H done -> in-place overwrite safe

        // epilogue STORE (the only work between the two barriers)
        #pragma unroll
        for (int mt = 0; mt < 4; ++mt)
            #pragma unroll
            for (int g = 0; g < 4; ++g) {
                const int mrow0 = mt * 32 + 8 * g + 4 * khalf;
                Hh[mrow0 + 0][ncol] = h16[mt][g][0];
                Hh[mrow0 + 1][ncol] = h16[mt][g][1];
                Hh[mrow0 + 2][ncol] = h16[mt][g][2];
                Hh[mrow0 + 3][ncol] = h16[mt][g][3];
            }
        __syncthreads();
    }

    // ---- final layer (128 -> 1): thread t reduces k-half (t&1) of row t>>1
    {
        const float b4v = b4[0];
        const int m = tid >> 1;
        const int q = tid & 1;
        float dot = 0.f;
        #pragma unroll
        for (int g = 0; g < 8; ++g) {
            const int f = 64 * q + 8 * g;
            const half8 hh = *(const half8*)&Hh[m][f];
            const float4 wa = *(const float4*)&W4[f];
            const float4 wb = *(const float4*)&W4[f + 4];
            dot = fmaf((float)hh[0], wa.x, dot);
            dot = fmaf((float)hh[1], wa.y, dot);
            dot = fmaf((float)hh[2], wa.z, dot);
            dot = fmaf((float)hh[3], wa.w, dot);
            dot = fmaf((float)hh[4], wb.x, dot);
            dot = fmaf((float)hh[5], wb.y, dot);
            dot = fmaf((float)hh[6], wb.z, dot);
            dot = fmaf((float)hh[7], wb.w, dot);
        }
        dot += __shfl_xor(dot, 1);   // full row-dot at both lanes of the pair

        if (is_eq) {
            // wave w holds rows [32w,32w+32) = points [8w,8w+8);
            // row r of point pl (=4pl+c) sits at lanes 8pl+2c (+q).
            const int base = (lane & 7) * 8;
            const float uu   = __shfl(dot, base + 0) + b4v;
            const float utv  = __shfl(dot, base + 2);
            const float uxv  = __shfl(dot, base + 4);
            const float uxxv = __shfl(dot, base + 6);
            if (lane < 8)
                out[blk * 32 + 8 * w + lane] = fmaf(uu, uxv, utv) - NU_F * uxxv;
        } else {
            if (q == 0)
                out[131072 + (blk - 4096) * 128 + m] = dot + b4v;
        }
    }
}

extern "C" void kernel_launch(void* const* d_in, const int* in_sizes, int n_in,
                              void* d_out, int out_size, void* d_ws, size_t ws_size,
                              hipStream_t stream)
{
    const float* tx_eq   = (const float*)d_in[0];
    const float* tx_init = (const float*)d_in[1];
    const float* tx_bnd  = (const float*)d_in[2];
    const float* W0 = (const float*)d_in[3];
    const float* b0 = (const float*)d_in[4];
    const float* W1 = (const float*)d_in[5];
    const float* b1 = (const float*)d_in[6];
    const float* W2 = (const float*)d_in[7];
    const float* b2 = (const float*)d_in[8];
    const float* W3 = (const float*)d_in[9];
    const float* b3 = (const float*)d_in[10];
    const float* W4 = (const float*)d_in[11];
    const float* b4 = (const float*)d_in[12];
    float* out = (float*)d_out;
    _Float16* wt = (_Float16*)d_ws;   // needs 98304 B

    hipLaunchKernelGGL(prep_kernel, dim3(192), dim3(256), 0, stream, W1, W2, W3, wt);
    // 4096 eq blocks (32 pts) + 64 ib blocks (128 pts)
    hipLaunchKernelGGL(pinn_kernel, dim3(4160), dim3(256), 0, stream,
                       tx_eq, tx_init, tx_bnd, W0, b0, b1, b2, b3, W4, b4,
                       (const _Float16*)wt, out);
}